// Round 1
// baseline (798.973 us; speedup 1.0000x reference)
//
#include <hip/hip_runtime.h>
#include <stdint.h>

// Problem constants (fixed by reference: R=C=256, S=32, B=64)
#define N_NEUR 65536
#define BATCH  64
#define NNZ_E  2162688   // N * 33

// Workspace layout (bytes):
//   xt      @ 0         : N*64*4 = 16,777,216   x transposed [N][64]
//   counts  @ 16777216  : N*4    = 262,144      per-row edge counts
//   offsets @ 17039360  : N*4    = 262,144      CSR row offsets (exclusive scan)
//   cursor  @ 17301504  : N*4    = 262,144      atomic append cursors
//   bsums   @ 17563648  : 256*4  (padded 4096)  block sums for scan
//   csr     @ 17567744  : NNZ*8  = 17,301,504   packed (col:int32 | val:f32)
// total ~34.9 MB

// ---------------- K1: transpose x [64][N] -> xt [N][64] ----------------
__global__ __launch_bounds__(256) void k_transpose_x(const float* __restrict__ x,
                                                     float* __restrict__ xt) {
  __shared__ float tile[64][65];   // +1 pad: conflict-free
  const int n0 = blockIdx.x * 64;
  const int lane = threadIdx.x & 63;
  const int w = threadIdx.x >> 6;
  #pragma unroll
  for (int bb = w; bb < 64; bb += 4)
    tile[bb][lane] = x[(size_t)bb * N_NEUR + n0 + lane];   // coalesced read
  __syncthreads();
  #pragma unroll
  for (int nn = w; nn < 64; nn += 4)
    xt[(size_t)(n0 + nn) * 64 + lane] = tile[lane][nn];    // coalesced write
}

// ---------------- K2: histogram of destination rows ----------------
__global__ __launch_bounds__(256) void k_hist(const int* __restrict__ rows,
                                              int* __restrict__ counts) {
  int i = blockIdx.x * 256 + threadIdx.x;   // grid sized exactly to NNZ
  atomicAdd(&counts[rows[i]], 1);
}

// ---------------- K3: hierarchical exclusive scan over N counts ----------------
__device__ inline int wave_incl_scan(int v, int lane) {
  #pragma unroll
  for (int off = 1; off < 64; off <<= 1) {
    int t = __shfl_up(v, off, 64);
    if (lane >= off) v += t;
  }
  return v;
}

__global__ __launch_bounds__(256) void k_scan_local(const int* __restrict__ counts,
                                                    int* __restrict__ offsets,
                                                    int* __restrict__ bsums) {
  const int tid = threadIdx.x;
  const int lane = tid & 63, w = tid >> 6;
  const int gid = blockIdx.x * 256 + tid;
  int v = counts[gid];
  int incl = wave_incl_scan(v, lane);
  __shared__ int wsum[4];
  if (lane == 63) wsum[w] = incl;
  __syncthreads();
  int base = 0;
  for (int i = 0; i < w; ++i) base += wsum[i];
  offsets[gid] = base + incl - v;              // block-local exclusive
  if (tid == 255) bsums[blockIdx.x] = base + incl;
}

__global__ __launch_bounds__(256) void k_scan_block(int* __restrict__ bsums) {
  const int tid = threadIdx.x;
  const int lane = tid & 63, w = tid >> 6;
  int v = bsums[tid];
  int incl = wave_incl_scan(v, lane);
  __shared__ int wsum[4];
  if (lane == 63) wsum[w] = incl;
  __syncthreads();
  int base = 0;
  for (int i = 0; i < w; ++i) base += wsum[i];
  bsums[tid] = base + incl - v;                // exclusive block offsets
}

__global__ __launch_bounds__(256) void k_scan_add(int* __restrict__ offsets,
                                                  const int* __restrict__ bsums,
                                                  int* __restrict__ cursor) {
  const int gid = blockIdx.x * 256 + threadIdx.x;
  const int o = offsets[gid] + bsums[blockIdx.x];
  offsets[gid] = o;
  cursor[gid]  = o;
}

// ---------------- K4: scatter edges into CSR (packed 8B entries) ----------------
__global__ __launch_bounds__(256) void k_scatter(const int* __restrict__ rows,
                                                 const int* __restrict__ cols,
                                                 const float* __restrict__ vals,
                                                 int* __restrict__ cursor,
                                                 uint64_t* __restrict__ csr) {
  int i = blockIdx.x * 256 + threadIdx.x;   // grid sized exactly to NNZ
  int r = rows[i];
  int pos = atomicAdd(&cursor[r], 1);
  uint64_t e = ((uint64_t)__float_as_uint(vals[i]) << 32) | (uint32_t)cols[i];
  csr[pos] = e;
}

// ---------------- K5: gather per destination row ----------------
__global__ __launch_bounds__(256) void k_gather(const float* __restrict__ xt,
                                                const int* __restrict__ offsets,
                                                const int* __restrict__ counts,
                                                const uint64_t* __restrict__ csr,
                                                float* __restrict__ out) {
  __shared__ float tile[64][65];
  // XCD-chunked swizzle: 1024 blocks, 8 XCDs -> each XCD gets a contiguous
  // 128-block (8192-row) chunk so its 4MB L2 holds the local xt window.
  const int bid = blockIdx.x;
  const int swz = (bid & 7) * 128 + (bid >> 3);
  const int r0 = swz * 64;
  const int lane = threadIdx.x & 63;   // batch index
  const int w = threadIdx.x >> 6;      // wave 0..3, each does 16 rows
  for (int i = 0; i < 16; ++i) {
    const int rl = w * 16 + i;
    const int r = r0 + rl;
    const int beg = offsets[r];
    const int cnt = counts[r];
    float acc = 0.f;
    for (int k = 0; k < cnt; ++k) {
      const uint64_t e = csr[beg + k];           // wave-uniform 8B broadcast
      const int col = (int)(uint32_t)e;
      const float v = __uint_as_float((uint32_t)(e >> 32));
      acc += v * xt[(size_t)col * 64 + lane];    // coalesced 256B line
    }
    tile[rl][lane] = acc;
  }
  __syncthreads();
  // transpose out of LDS: out[b][r0+lane], coalesced along lane
  #pragma unroll
  for (int i = 0; i < 16; ++i) {
    const int b = w * 16 + i;
    out[(size_t)b * N_NEUR + r0 + lane] = tile[lane][b];
  }
}

extern "C" void kernel_launch(void* const* d_in, const int* in_sizes, int n_in,
                              void* d_out, int out_size, void* d_ws, size_t ws_size,
                              hipStream_t stream) {
  const float* x    = (const float*)d_in[0];
  const float* vals = (const float*)d_in[1];
  const int*   rows = (const int*)d_in[2];
  const int*   cols = (const int*)d_in[3];
  float* out = (float*)d_out;

  char* ws = (char*)d_ws;
  float*    xt      = (float*)   (ws + 0);
  int*      counts  = (int*)     (ws + 16777216);
  int*      offsets = (int*)     (ws + 17039360);
  int*      cursor  = (int*)     (ws + 17301504);
  int*      bsums   = (int*)     (ws + 17563648);
  uint64_t* csr     = (uint64_t*)(ws + 17567744);

  hipMemsetAsync(counts, 0, N_NEUR * sizeof(int), stream);
  k_transpose_x<<<N_NEUR / 64, 256, 0, stream>>>(x, xt);
  k_hist<<<NNZ_E / 256, 256, 0, stream>>>(rows, counts);
  k_scan_local<<<N_NEUR / 256, 256, 0, stream>>>(counts, offsets, bsums);
  k_scan_block<<<1, 256, 0, stream>>>(bsums);
  k_scan_add<<<N_NEUR / 256, 256, 0, stream>>>(offsets, bsums, cursor);
  k_scatter<<<NNZ_E / 256, 256, 0, stream>>>(rows, cols, vals, cursor, csr);
  k_gather<<<N_NEUR / 64, 256, 0, stream>>>(xt, offsets, counts, csr, out);
}

// Round 2
// 329.772 us; speedup vs baseline: 2.4228x; 2.4228x over previous
//
#include <hip/hip_runtime.h>
#include <stdint.h>

// Problem constants (fixed by reference: R=C=256, S=32, B=64)
#define N_NEUR 65536
#define BATCH  64
#define NNZ_E  2162688   // N * 33

// Workspace layout (bytes):
//   xt      @ 0         : N*64*4 = 16,777,216   x transposed [N][64]
//   counts  @ 16777216  : N*4    = 262,144
//   offsets @ 17039360  : N*4    = 262,144
//   cursor  @ 17301504  : N*4    = 262,144
//   bsums   @ 17563648  : 256*4 (padded 4096)
//   csr     @ 17567744  : NNZ*8  = 17,301,504   packed (val:f32 hi | col:u32 lo)

// ---------------- K1: transpose x [64][N] -> xt [N][64] ----------------
__global__ __launch_bounds__(256) void k_transpose_x(const float* __restrict__ x,
                                                     float* __restrict__ xt) {
  __shared__ float tile[64][65];
  const int n0 = blockIdx.x * 64;
  const int lane = threadIdx.x & 63;
  const int w = threadIdx.x >> 6;
  #pragma unroll
  for (int bb = w; bb < 64; bb += 4)
    tile[bb][lane] = x[(size_t)bb * N_NEUR + n0 + lane];
  __syncthreads();
  #pragma unroll
  for (int nn = w; nn < 64; nn += 4)
    xt[(size_t)(n0 + nn) * 64 + lane] = tile[lane][nn];
}

// ---------------- K2: histogram of destination rows (4 edges/thread) ----------------
__global__ __launch_bounds__(256) void k_hist(const int* __restrict__ rows,
                                              int* __restrict__ counts) {
  const int i = (blockIdx.x * 256 + threadIdx.x) * 4;   // grid*1024 == NNZ
  const int4 r = *(const int4*)(rows + i);
  atomicAdd(&counts[r.x], 1);
  atomicAdd(&counts[r.y], 1);
  atomicAdd(&counts[r.z], 1);
  atomicAdd(&counts[r.w], 1);
}

// ---------------- K3: hierarchical exclusive scan ----------------
__device__ inline int wave_incl_scan(int v, int lane) {
  #pragma unroll
  for (int off = 1; off < 64; off <<= 1) {
    int t = __shfl_up(v, off, 64);
    if (lane >= off) v += t;
  }
  return v;
}

__global__ __launch_bounds__(256) void k_scan_local(const int* __restrict__ counts,
                                                    int* __restrict__ offsets,
                                                    int* __restrict__ bsums) {
  const int tid = threadIdx.x;
  const int lane = tid & 63, w = tid >> 6;
  const int gid = blockIdx.x * 256 + tid;
  int v = counts[gid];
  int incl = wave_incl_scan(v, lane);
  __shared__ int wsum[4];
  if (lane == 63) wsum[w] = incl;
  __syncthreads();
  int base = 0;
  for (int i = 0; i < w; ++i) base += wsum[i];
  offsets[gid] = base + incl - v;
  if (tid == 255) bsums[blockIdx.x] = base + incl;
}

__global__ __launch_bounds__(256) void k_scan_block(int* __restrict__ bsums) {
  const int tid = threadIdx.x;
  const int lane = tid & 63, w = tid >> 6;
  int v = bsums[tid];
  int incl = wave_incl_scan(v, lane);
  __shared__ int wsum[4];
  if (lane == 63) wsum[w] = incl;
  __syncthreads();
  int base = 0;
  for (int i = 0; i < w; ++i) base += wsum[i];
  bsums[tid] = base + incl - v;
}

__global__ __launch_bounds__(256) void k_scan_add(int* __restrict__ offsets,
                                                  const int* __restrict__ bsums,
                                                  int* __restrict__ cursor) {
  const int gid = blockIdx.x * 256 + threadIdx.x;
  const int o = offsets[gid] + bsums[blockIdx.x];
  offsets[gid] = o;
  cursor[gid]  = o;
}

// ---------------- K4: scatter edges into CSR (4 edges/thread) ----------------
__global__ __launch_bounds__(256) void k_scatter(const int* __restrict__ rows,
                                                 const int* __restrict__ cols,
                                                 const float* __restrict__ vals,
                                                 int* __restrict__ cursor,
                                                 uint64_t* __restrict__ csr) {
  const int i = (blockIdx.x * 256 + threadIdx.x) * 4;
  const int4   r4 = *(const int4*)(rows + i);
  const int4   c4 = *(const int4*)(cols + i);
  const float4 v4 = *(const float4*)(vals + i);
  int p;
  p = atomicAdd(&cursor[r4.x], 1);
  csr[p] = ((uint64_t)__float_as_uint(v4.x) << 32) | (uint32_t)c4.x;
  p = atomicAdd(&cursor[r4.y], 1);
  csr[p] = ((uint64_t)__float_as_uint(v4.y) << 32) | (uint32_t)c4.y;
  p = atomicAdd(&cursor[r4.z], 1);
  csr[p] = ((uint64_t)__float_as_uint(v4.z) << 32) | (uint32_t)c4.z;
  p = atomicAdd(&cursor[r4.w], 1);
  csr[p] = ((uint64_t)__float_as_uint(v4.w) << 32) | (uint32_t)c4.w;
}

// ---------------- K5: gather per destination row, 8-wide MLP unroll ----------------
// 2048 blocks x 32 rows; wave w handles rows w*8..w*8+7; lane = batch index.
__global__ __launch_bounds__(256) void k_gather2(const float* __restrict__ xt,
                                                 const int* __restrict__ offsets,
                                                 const int* __restrict__ counts,
                                                 const uint64_t* __restrict__ csr,
                                                 float* __restrict__ out) {
  __shared__ float tile[32][69];   // pad 69: 5*rl+b covers all 32 banks
  const int bid = blockIdx.x;
  const int swz = (bid & 7) * 256 + (bid >> 3);   // XCD-chunked: 8 chunks of 256
  const int r0 = swz * 32;
  const int lane = threadIdx.x & 63;
  const int w = threadIdx.x >> 6;

  for (int i = 0; i < 8; ++i) {
    const int rl = w * 8 + i;
    const int r = r0 + rl;
    const int beg = __builtin_amdgcn_readfirstlane(offsets[r]);
    const int cnt = __builtin_amdgcn_readfirstlane(counts[r]);
    const uint64_t* ep = csr + beg;
    float acc0 = 0.f, acc1 = 0.f;
    int k = 0;
    for (; k + 8 <= cnt; k += 8) {
      const uint64_t e0 = ep[k+0], e1 = ep[k+1], e2 = ep[k+2], e3 = ep[k+3];
      const uint64_t e4 = ep[k+4], e5 = ep[k+5], e6 = ep[k+6], e7 = ep[k+7];
      const float p0 = xt[(int)(uint32_t)e0 * 64 + lane];
      const float p1 = xt[(int)(uint32_t)e1 * 64 + lane];
      const float p2 = xt[(int)(uint32_t)e2 * 64 + lane];
      const float p3 = xt[(int)(uint32_t)e3 * 64 + lane];
      const float p4 = xt[(int)(uint32_t)e4 * 64 + lane];
      const float p5 = xt[(int)(uint32_t)e5 * 64 + lane];
      const float p6 = xt[(int)(uint32_t)e6 * 64 + lane];
      const float p7 = xt[(int)(uint32_t)e7 * 64 + lane];
      acc0 = fmaf(__uint_as_float((uint32_t)(e0 >> 32)), p0, acc0);
      acc1 = fmaf(__uint_as_float((uint32_t)(e1 >> 32)), p1, acc1);
      acc0 = fmaf(__uint_as_float((uint32_t)(e2 >> 32)), p2, acc0);
      acc1 = fmaf(__uint_as_float((uint32_t)(e3 >> 32)), p3, acc1);
      acc0 = fmaf(__uint_as_float((uint32_t)(e4 >> 32)), p4, acc0);
      acc1 = fmaf(__uint_as_float((uint32_t)(e5 >> 32)), p5, acc1);
      acc0 = fmaf(__uint_as_float((uint32_t)(e6 >> 32)), p6, acc0);
      acc1 = fmaf(__uint_as_float((uint32_t)(e7 >> 32)), p7, acc1);
    }
    for (; k < cnt; ++k) {
      const uint64_t e = ep[k];
      acc0 = fmaf(__uint_as_float((uint32_t)(e >> 32)),
                  xt[(int)(uint32_t)e * 64 + lane], acc0);
    }
    tile[rl][lane] = acc0 + acc1;
  }
  __syncthreads();
  // coalesced write-out: 2048 floats, 128B segments per half-wave
  #pragma unroll
  for (int p = 0; p < 8; ++p) {
    const int idx = p * 256 + threadIdx.x;
    const int b = idx >> 5, rl = idx & 31;
    out[(size_t)b * N_NEUR + r0 + rl] = tile[rl][b];
  }
}

extern "C" void kernel_launch(void* const* d_in, const int* in_sizes, int n_in,
                              void* d_out, int out_size, void* d_ws, size_t ws_size,
                              hipStream_t stream) {
  const float* x    = (const float*)d_in[0];
  const float* vals = (const float*)d_in[1];
  const int*   rows = (const int*)d_in[2];
  const int*   cols = (const int*)d_in[3];
  float* out = (float*)d_out;

  char* ws = (char*)d_ws;
  float*    xt      = (float*)   (ws + 0);
  int*      counts  = (int*)     (ws + 16777216);
  int*      offsets = (int*)     (ws + 17039360);
  int*      cursor  = (int*)     (ws + 17301504);
  int*      bsums   = (int*)     (ws + 17563648);
  uint64_t* csr     = (uint64_t*)(ws + 17567744);

  hipMemsetAsync(counts, 0, N_NEUR * sizeof(int), stream);
  k_transpose_x<<<N_NEUR / 64, 256, 0, stream>>>(x, xt);
  k_hist<<<NNZ_E / 1024, 256, 0, stream>>>(rows, counts);
  k_scan_local<<<N_NEUR / 256, 256, 0, stream>>>(counts, offsets, bsums);
  k_scan_block<<<1, 256, 0, stream>>>(bsums);
  k_scan_add<<<N_NEUR / 256, 256, 0, stream>>>(offsets, bsums, cursor);
  k_scatter<<<NNZ_E / 1024, 256, 0, stream>>>(rows, cols, vals, cursor, csr);
  k_gather2<<<N_NEUR / 32, 256, 0, stream>>>(xt, offsets, counts, csr, out);
}